// Round 1
// baseline (121.362 us; speedup 1.0000x reference)
//
#include <hip/hip_runtime.h>
#include <hip/hip_bf16.h>

typedef _Float16 half2v __attribute__((ext_vector_type(2)));
typedef _Float16 half8 __attribute__((ext_vector_type(8)));
typedef __attribute__((ext_vector_type(4))) float floatx4;
typedef __attribute__((ext_vector_type(4))) unsigned int uintx4;

#define GLOBAL_AS __attribute__((address_space(1)))
#define LDS_AS __attribute__((address_space(3)))

// async 16B/lane global->LDS DMA. LDS dest = WAVE-uniform base + lane*16.
__device__ __forceinline__ void async_ld16(const void* g, void* l) {
  __builtin_amdgcn_global_load_lds((const GLOBAL_AS unsigned int*)g,
                                   (LDS_AS unsigned int*)l, 16, 0, 0);
}

__device__ __forceinline__ half2v h2(float v) {
  return (half2v){(_Float16)v, (_Float16)v};
}

// tanh(x0),tanh(x1) -> packed-f16 Legendre P1..P8 for BOTH elements.
// fa0 = low halves (elem0), fa1 = high halves (elem1). ~42 VALU total.
__device__ __forceinline__ void legendre2_f16(float xv0, float xv1,
                                              half8* fa0, half8* fa1) {
  float e0 = __builtin_amdgcn_exp2f(xv0 * 2.885390081777927f); // 2*log2(e)
  float t0 = 1.0f - 2.0f * __builtin_amdgcn_rcpf(e0 + 1.0f);
  float e1 = __builtin_amdgcn_exp2f(xv1 * 2.885390081777927f);
  float t1 = 1.0f - 2.0f * __builtin_amdgcn_rcpf(e1 + 1.0f);
  half2v t;
  { auto tt = __builtin_amdgcn_cvt_pkrtz(t0, t1); __builtin_memcpy(&t, &tt, 4); }
  // P_k = u + c_k*(u - P_{k-2}), u = t*P_{k-1}, c_k=(k-1)/k   (packed, 3 ops/deg)
  half2v p1 = t;
  half2v u2 = t * p1, w2 = u2 - h2(1.0f);  half2v p2 = h2(0.5f)      * w2 + u2;
  half2v u3 = t * p2, w3 = u3 - p1;        half2v p3 = h2(2.0f/3.0f) * w3 + u3;
  half2v u4 = t * p3, w4 = u4 - p2;        half2v p4 = h2(0.75f)     * w4 + u4;
  half2v u5 = t * p4, w5 = u5 - p3;        half2v p5 = h2(0.8f)      * w5 + u5;
  half2v u6 = t * p5, w6 = u6 - p4;        half2v p6 = h2(5.0f/6.0f) * w6 + u6;
  half2v u7 = t * p6, w7 = u7 - p5;        half2v p7 = h2(6.0f/7.0f) * w7 + u7;
  half2v u8 = t * p7, w8 = u8 - p6;        half2v p8 = h2(7.0f/8.0f) * w8 + u8;
  unsigned P[8];
  __builtin_memcpy(&P[0], &p1, 4); __builtin_memcpy(&P[1], &p2, 4);
  __builtin_memcpy(&P[2], &p3, 4); __builtin_memcpy(&P[3], &p4, 4);
  __builtin_memcpy(&P[4], &p5, 4); __builtin_memcpy(&P[5], &p6, 4);
  __builtin_memcpy(&P[6], &p7, 4); __builtin_memcpy(&P[7], &p8, 4);
  union { unsigned u[4]; half8 h; } a0, a1;
#pragma unroll
  for (int j = 0; j < 4; ++j) {
    a0.u[j] = __builtin_amdgcn_perm(P[2*j+1], P[2*j], 0x05040100u); // low halves
    a1.u[j] = __builtin_amdgcn_perm(P[2*j+1], P[2*j], 0x07060302u); // high halves
  }
  *fa0 = a0.h;
  *fa1 = a1.h;
}

// ---- kernel 1: c_basis fp32 -> f16, transposed to ws[i][o][d] (256 KB) ----
__global__ void conv_kernel(const float* __restrict__ cb, _Float16* __restrict__ ws) {
  int t = blockIdx.x * 128 + threadIdx.x;   // 0..16383 = (o,i)
  int o = t >> 8;
  int i = t & 255;
  const floatx4* s = (const floatx4*)(cb + ((size_t)o * 256 + i) * 8);
  floatx4 v0 = s[0], v1 = s[1];
  union { _Float16 h[8]; uintx4 u; } w;
  w.h[0] = (_Float16)v0.x; w.h[1] = (_Float16)v0.y;
  w.h[2] = (_Float16)v0.z; w.h[3] = (_Float16)v0.w;
  w.h[4] = (_Float16)v1.x; w.h[5] = (_Float16)v1.y;
  w.h[6] = (_Float16)v1.z; w.h[7] = (_Float16)v1.w;
  *(uintx4*)(ws + (size_t)i * 512 + o * 8) = w.u;
}

// ---- kernel 2 ----
// 128 thr (2 waves), 64 rows/block, grid 1024 -> 4 blocks/CU (LDS 32 KB).
// B double-buffered through LDS via DMA (8 slots/wave/chunk, vmcnt(10)-gated,
// WAR+RAW barrier pair per chunk — verified structure). x bypasses LDS:
// K-slot remap i = ch*16 + q*4 + j makes each lane's per-chunk x a contiguous
// float4, register-prefetched 2 chunks ahead. Legendre hoisted above the WAR
// barrier so the barrier-bracketed section is pure ds_read+MFMA (role-split
// between the 2 waves; setprio(1) around MFMA cluster).
#define NCH 16

__global__ __launch_bounds__(128, 2) void kan_kernel(
    const float* __restrict__ x, const _Float16* __restrict__ ws,
    const float* __restrict__ bias, float* __restrict__ y) {
  __shared__ __align__(16) _Float16 bt[2][16 * 64 * 8]; // 2 x 16 KB

  const int tid  = threadIdx.x;
  const int wid  = tid >> 6;    // 0..1
  const int lane = tid & 63;
  const int m    = lane & 15;
  const int q    = lane >> 4;
  const int row_block = blockIdx.x * 64;

  floatx4 acc[2][4];
#pragma unroll
  for (int a = 0; a < 2; ++a)
#pragma unroll
    for (int nt = 0; nt < 4; ++nt) acc[a][nt] = (floatx4){0.f, 0.f, 0.f, 0.f};

  // persistent B staging pointers (advance once per chunk)
  const _Float16* bsrc[8];
#pragma unroll
  for (int t = 0; t < 8; ++t)
    bsrc[t] = ws + (size_t)(t * 128 + wid * 64 + lane) * 8;

  // x: rows r0 = row_block + wid*32 + m, r1 = r0 + 16. Per chunk each lane
  // needs cols [ch*16 + q*4 .. +3]  ->  one aligned float4 per row-stream.
  const float* xp0 = x + (size_t)(row_block + wid * 32 + m) * 256 + q * 4;
  const float* xp1 = xp0 + 16 * 256;

  floatx4 xa0 = *(const floatx4*)xp0;          // chunk 0
  floatx4 xa1 = *(const floatx4*)xp1;
  floatx4 xb0 = *(const floatx4*)(xp0 + 16);   // chunk 1
  floatx4 xb1 = *(const floatx4*)(xp1 + 16);
  xp0 += 32; xp1 += 32;                        // -> chunk 2

  // 8 DMAs per wave per chunk: B only (16 KB/chunk/block)
  auto stage = [&](int b) {
#pragma unroll
    for (int t = 0; t < 8; ++t) {
      int sb = t * 128 + wid * 64;
      async_ld16(bsrc[t], &bt[b][sb * 8]);
      bsrc[t] += 8192;
    }
  };

  stage(0);

#pragma unroll 2
  for (int ch = 0; ch < NCH; ++ch) {
    const int buf = ch & 1;

    // legendre for chunk ch (registers only, before any sync): 4 j-pairs,
    // f0[j] = rows r0 fragment, f1[j] = rows r1 fragment, i = ch*16+q*4+j
    half8 f0[4], f1[4];
#pragma unroll
    for (int j = 0; j < 4; ++j)
      legendre2_f16(xa0[j], xa1[j], &f0[j], &f1[j]);

    // WAR: all waves done computing chunk ch-1 (which read buf^1)
    asm volatile("s_barrier" ::: "memory");

    floatx4 xn0 = xb0, xn1 = xb1;
    if (ch + 1 < NCH) {
      stage(buf ^ 1);                      // 8 DMAs for chunk ch+1
      if (ch + 2 < NCH) {                  // register-prefetch x for chunk ch+2
        xn0 = *(const floatx4*)xp0;
        xn1 = *(const floatx4*)xp1;
        xp0 += 16; xp1 += 16;
      }
      // FIFO: [stage(ch) 8][x(ch+1) 2][stage(ch+1) 8][x(ch+2) 0..2]
      // vmcnt(10) drains stage(ch) (+ the already-landed x(ch+1)).
      asm volatile("s_waitcnt vmcnt(10)" ::: "memory");
    } else {
      asm volatile("s_waitcnt vmcnt(0)" ::: "memory");
    }
    // RAW: ALL waves' chunk-ch B slices landed
    asm volatile("s_barrier" ::: "memory");

    __builtin_amdgcn_s_setprio(1);
    // B frags: i_local = q*4 + j  ->  halves offset q*2048 + j*512 + nt*128 + m*8
    const _Float16* bp = &bt[buf][q * 2048 + m * 8];
#pragma unroll
    for (int j = 0; j < 4; ++j) {
      half8 fb0 = *(const half8*)(bp + j * 512 + 0 * 128);
      half8 fb1 = *(const half8*)(bp + j * 512 + 1 * 128);
      half8 fb2 = *(const half8*)(bp + j * 512 + 2 * 128);
      half8 fb3 = *(const half8*)(bp + j * 512 + 3 * 128);
      acc[0][0] = __builtin_amdgcn_mfma_f32_16x16x32_f16(f0[j], fb0, acc[0][0], 0, 0, 0);
      acc[1][0] = __builtin_amdgcn_mfma_f32_16x16x32_f16(f1[j], fb0, acc[1][0], 0, 0, 0);
      acc[0][1] = __builtin_amdgcn_mfma_f32_16x16x32_f16(f0[j], fb1, acc[0][1], 0, 0, 0);
      acc[1][1] = __builtin_amdgcn_mfma_f32_16x16x32_f16(f1[j], fb1, acc[1][1], 0, 0, 0);
      acc[0][2] = __builtin_amdgcn_mfma_f32_16x16x32_f16(f0[j], fb2, acc[0][2], 0, 0, 0);
      acc[1][2] = __builtin_amdgcn_mfma_f32_16x16x32_f16(f1[j], fb2, acc[1][2], 0, 0, 0);
      acc[0][3] = __builtin_amdgcn_mfma_f32_16x16x32_f16(f0[j], fb3, acc[0][3], 0, 0, 0);
      acc[1][3] = __builtin_amdgcn_mfma_f32_16x16x32_f16(f1[j], fb3, acc[1][3], 0, 0, 0);
    }
    __builtin_amdgcn_s_setprio(0);

    // rotate x pipeline
    xa0 = xb0; xa1 = xb1; xb0 = xn0; xb1 = xn1;
  }

  // epilogue: D[row=(q*4+reg)][col=m], add bias (layout verified R1-R6)
  float bv[4];
#pragma unroll
  for (int nt = 0; nt < 4; ++nt) bv[nt] = bias[nt * 16 + m];
#pragma unroll
  for (int a = 0; a < 2; ++a) {
    int gr0 = row_block + wid * 32 + a * 16 + q * 4;
#pragma unroll
    for (int nt = 0; nt < 4; ++nt) {
#pragma unroll
      for (int r = 0; r < 4; ++r) {
        y[(size_t)(gr0 + r) * 64 + nt * 16 + m] = acc[a][nt][r] + bv[nt];
      }
    }
  }
}

extern "C" void kernel_launch(void* const* d_in, const int* in_sizes, int n_in,
                              void* d_out, int out_size, void* d_ws, size_t ws_size,
                              hipStream_t stream) {
  const float* x    = (const float*)d_in[0];
  const float* cb   = (const float*)d_in[1];
  const float* bias = (const float*)d_in[2];
  float* y = (float*)d_out;
  _Float16* ws = (_Float16*)d_ws;
  int batch = in_sizes[0] / 256;  // 65536
  hipLaunchKernelGGL(conv_kernel, dim3(128), dim3(128), 0, stream, cb, ws);
  hipLaunchKernelGGL(kan_kernel, dim3(batch / 64), dim3(128), 0, stream, x, ws, bias, y);
}